// Round 4
// baseline (272.362 us; speedup 1.0000x reference)
//
#include <hip/hip_runtime.h>

// ROIAlign forward (PH=PW=7, SCALE=0.25, SR=2, ALIGNED=true)
//   input [4,256,200,200] fp32 NCHW, rois [512,5], out [512,256,7,7] fp32
//
// R5 design: strip-LDS gather + precomputed geometry + 4 blocks/CU.
//   - Fixed harness overhead (~160us: 640MB d_ws poison @100us + input
//     restore + out poison) is untouchable; roi_strip was ~100us vs ~40us
//     floor (staging 188MB ~29us + compute ~12us).
//   - R5a: geometry (bilinear indices+weights) is channel-independent but was
//     recomputed 256x per (n,ph,pw) (~90 VALU + 5 scattered roi loads per
//     item). build_tables now precomputes:
//       * per-(n,ph) bucket records: 48B = {xtab base, out base, 4 row word
//         offsets rel. to strip, 4 y-weights pre-scaled by 0.25}
//       * per-(n,pw,q) x-table: {xlo, xhi, wxl, wxh} float4 — a wave's 7 pw
//         lanes read 224B contiguous, L2-hot (114KB, reused 256x).
//     Hot loop: 3 broadcast rec loads + 2 coalesced xtab loads + 16 LDS taps
//     + 16 FMA + 1 store. No rois access, no axis_sample.
//   - R5b: STRIP 50->40 (NSTRIP=5, STAGE_ROWS=46): LDS 44.8->36.8 KB ->
//     4 blocks/CU -> 32 waves/CU (occupancy cap), +33% latency hiding.
//   - Cover proof: binh <= 64/7 -> sample-1 coord <= coord0+4.58 -> tap rows
//     <= lo0+6; STAGE_ROWS = STRIP+6 = 46. Edge clamp (row 199) only when
//     lo0 >= 194 -> bucket 4 -> staged. Bucket = lo0/40 with lo0 = min row.

#define R_PH 7
#define R_PW 7
#define R_SR 2
#define R_SCALE 0.25f
#define R_C 256
#define R_H 200
#define R_W 200
#define R_HW (R_H * R_W)
#define STRIP 40
#define NSTRIP 5
#define STAGE_ROWS 46   // STRIP + 6

__device__ __forceinline__ void axis_sample(float start, float bin, int p, int s, int size,
                                            int& lo, int& hi, float& wlo, float& whi) {
    // coord = start + p*bin + (s+0.5)*bin/SR   (same grouping as reference)
    float coord = (start + (float)p * bin) + ((float)s + 0.5f) * bin * (1.0f / R_SR);
    bool valid = (coord >= -1.0f) && (coord <= (float)size);
    float c = fmaxf(coord, 0.0f);
    int lo_raw = (int)floorf(c);
    bool at_edge = lo_raw >= size - 1;
    lo = at_edge ? size - 1 : lo_raw;
    hi = at_edge ? size - 1 : lo_raw + 1;
    float cv = at_edge ? (float)(size - 1) : c;
    float frac = cv - (float)lo;          // weight toward hi
    whi = valid ? frac : 0.0f;
    wlo = valid ? (1.0f - frac) : 0.0f;
}

// ---------- ws layout (ints) ----------
// [0..31]           : bucket counts (20 used: b*NSTRIP+s)
// [32 .. 32+N*56)   : x-table, float4[N*14]: (n,pw,q) -> {asint(xlo), asint(xhi), wxl, wxh}
// [32+N*56 .. )     : records, int4[20][N*7][3]:
//    rec0 = {xbase(=n*14), obase(=n*12544+ph*7), (ylo0-r0)*200, (yhi0-r0)*200}
//    rec1 = {(ylo1-r0)*200, (yhi1-r0)*200, asint(wyl0*0.25), asint(wyh0*0.25)}
//    rec2 = {asint(wyl1*0.25), asint(wyh1*0.25), 0, 0}

__global__ void __launch_bounds__(512)
build_tables(const float* __restrict__ rois, int N, int* __restrict__ ws) {
    __shared__ int lcnt[32];
    int t = threadIdx.x;
    if (t < 32) lcnt[t] = 0;
    __syncthreads();
    float4* xtab = (float4*)(ws + 32);
    int4*   recs = (int4*)(ws + 32 + N * 56);
    for (int n = t; n < N; n += 512) {
        const float* r = rois + (size_t)n * 5;
        int b = (int)r[0];
        float sx = r[1] * R_SCALE - 0.5f;
        float sy = r[2] * R_SCALE - 0.5f;
        float ex = r[3] * R_SCALE - 0.5f;
        float ey = r[4] * R_SCALE - 0.5f;
        float binw = (ex - sx) * (1.0f / R_PW);
        float binh = (ey - sy) * (1.0f / R_PH);
        // x geometry table
        for (int pw = 0; pw < R_PW; ++pw) {
            for (int q = 0; q < R_SR; ++q) {
                int lo, hi; float wl, wh;
                axis_sample(sx, binw, pw, q, R_W, lo, hi, wl, wh);
                xtab[n * 14 + pw * 2 + q] =
                    make_float4(__int_as_float(lo), __int_as_float(hi), wl, wh);
            }
        }
        // y geometry + bucket record per ph
        for (int ph = 0; ph < R_PH; ++ph) {
            int lo0, hi0, lo1, hi1; float wl0, wh0, wl1, wh1;
            axis_sample(sy, binh, ph, 0, R_H, lo0, hi0, wl0, wh0);
            axis_sample(sy, binh, ph, 1, R_H, lo1, hi1, wl1, wh1);
            int s  = lo0 / STRIP;                 // lo0 = min row touched
            int bs = b * NSTRIP + s;
            int r0 = s * STRIP;
            int pos = atomicAdd(&lcnt[bs], 1);
            int4* rec = recs + ((size_t)bs * N * R_PH + pos) * 3;
            rec[0] = make_int4(n * 14, n * (R_C * 49) + ph * R_PW,
                               (lo0 - r0) * R_W, (hi0 - r0) * R_W);
            rec[1] = make_int4((lo1 - r0) * R_W, (hi1 - r0) * R_W,
                               __float_as_int(wl0 * 0.25f), __float_as_int(wh0 * 0.25f));
            rec[2] = make_int4(__float_as_int(wl1 * 0.25f), __float_as_int(wh1 * 0.25f), 0, 0);
        }
    }
    __syncthreads();
    if (t < 32) ws[t] = lcnt[t];
}

// ---------- Main: strip-LDS gather with precomputed geometry ----------
// grid (C=256, B=4, NSTRIP=5), block 512, 36.8 KB LDS -> 4 blocks/CU
__global__ void __launch_bounds__(512)
roi_strip(const float* __restrict__ input,
          const int* __restrict__ ws, int N,
          float* __restrict__ out) {
    __shared__ float pl[STAGE_ROWS * R_W];   // 36800 B
    int c = blockIdx.x;
    int b = blockIdx.y;
    int s = blockIdx.z;
    int bs = b * NSTRIP + s;

    int m = ws[bs];
    if (m == 0) return;

    int r0 = s * STRIP;
    int nrows = min(STAGE_ROWS, R_H - r0);

    const float4* src = (const float4*)(input + (size_t)(b * R_C + c) * R_HW + r0 * R_W);
    float4* dstv = (float4*)pl;
    int nf4 = nrows * (R_W / 4);
    for (int i = threadIdx.x; i < nf4; i += 512) dstv[i] = src[i];

    const float4* xtab = (const float4*)(ws + 32);
    const int4*   recs = (const int4*)(ws + 32 + N * 56) + (size_t)bs * N * R_PH * 3;
    __syncthreads();

    int total = m * R_PW;
    int cbase = c * 49;
    for (int i = threadIdx.x; i < total; i += 512) {
        int e  = i / R_PW;
        int pw = i - e * R_PW;
        int4 ra = recs[e * 3 + 0];
        int4 rb = recs[e * 3 + 1];
        int4 rc = recs[e * 3 + 2];
        float4 xg0 = xtab[ra.x + pw * 2];
        float4 xg1 = xtab[ra.x + pw * 2 + 1];
        int xl0 = __float_as_int(xg0.x), xh0 = __float_as_int(xg0.y);
        int xl1 = __float_as_int(xg1.x), xh1 = __float_as_int(xg1.y);
        float wxl0 = xg0.z, wxh0 = xg0.w;
        float wxl1 = xg1.z, wxh1 = xg1.w;
        const float* rl0 = pl + ra.z;
        const float* rh0 = pl + ra.w;
        const float* rl1 = pl + rb.x;
        const float* rh1 = pl + rb.y;
        float wyl0 = __int_as_float(rb.z), wyh0 = __int_as_float(rb.w);
        float wyl1 = __int_as_float(rc.x), wyh1 = __int_as_float(rc.y);

        float acc =
              wyl0 * (wxl0 * rl0[xl0] + wxh0 * rl0[xh0] + wxl1 * rl0[xl1] + wxh1 * rl0[xh1])
            + wyh0 * (wxl0 * rh0[xl0] + wxh0 * rh0[xh0] + wxl1 * rh0[xl1] + wxh1 * rh0[xh1])
            + wyl1 * (wxl0 * rl1[xl0] + wxh0 * rl1[xh0] + wxl1 * rl1[xl1] + wxh1 * rl1[xh1])
            + wyh1 * (wxl0 * rh1[xl0] + wxh0 * rh1[xh0] + wxl1 * rh1[xl1] + wxh1 * rh1[xh1]);

        out[ra.y + cbase + pw] = acc;   // y-weights pre-scaled by 0.25
    }
}

// ---------- Fallback: single-pass kernel (if ws too small) ----------
__global__ void __launch_bounds__(256)
roi_align_fwd(const float* __restrict__ input,
              const float* __restrict__ rois,
              float* __restrict__ out, int total) {
    int idx = blockIdx.x * blockDim.x + threadIdx.x;
    if (idx >= total) return;
    int pw = idx % R_PW;
    int ph = (idx / R_PW) % R_PH;
    int c  = (idx / (R_PW * R_PH)) % R_C;
    int n  = idx / (R_PW * R_PH * R_C);
    const float* r = rois + (size_t)n * 5;
    int   b  = (int)r[0];
    float sx = r[1] * R_SCALE - 0.5f;
    float sy = r[2] * R_SCALE - 0.5f;
    float ex = r[3] * R_SCALE - 0.5f;
    float ey = r[4] * R_SCALE - 0.5f;
    float bin_w = (ex - sx) * (1.0f / R_PW);
    float bin_h = (ey - sy) * (1.0f / R_PH);
    const float* plane = input + (size_t)(b * R_C + c) * R_HW;
    int   ylo[R_SR], yhi[R_SR], xlo[R_SR], xhi[R_SR];
    float wylo[R_SR], wyhi[R_SR], wxlo[R_SR], wxhi[R_SR];
#pragma unroll
    for (int s = 0; s < R_SR; ++s) {
        axis_sample(sy, bin_h, ph, s, R_H, ylo[s], yhi[s], wylo[s], wyhi[s]);
        axis_sample(sx, bin_w, pw, s, R_W, xlo[s], xhi[s], wxlo[s], wxhi[s]);
    }
    float acc = 0.0f;
#pragma unroll
    for (int ys = 0; ys < R_SR; ++ys) {
        const float* row_lo = plane + ylo[ys] * R_W;
        const float* row_hi = plane + yhi[ys] * R_W;
#pragma unroll
        for (int xs = 0; xs < R_SR; ++xs) {
            acc += wylo[ys] * (wxlo[xs] * row_lo[xlo[xs]] + wxhi[xs] * row_lo[xhi[xs]])
                 + wyhi[ys] * (wxlo[xs] * row_hi[xlo[xs]] + wxhi[xs] * row_hi[xhi[xs]]);
        }
    }
    out[idx] = acc * (1.0f / (R_SR * R_SR));
}

extern "C" void kernel_launch(void* const* d_in, const int* in_sizes, int n_in,
                              void* d_out, int out_size, void* d_ws, size_t ws_size,
                              hipStream_t stream) {
    const float* input = (const float*)d_in[0];
    const float* rois  = (const float*)d_in[1];
    float* out = (float*)d_out;
    int N = in_sizes[1] / 5;

    // ints: 32 cnt + N*56 xtab + 20 buckets * N*7 recs * 12 ints
    size_t ws_needed = (size_t)(32 + (size_t)N * 56 +
                                (size_t)NSTRIP * 4 * N * R_PH * 12) * sizeof(int);
    if (ws_size >= ws_needed) {
        int* ws = (int*)d_ws;
        build_tables<<<1, 512, 0, stream>>>(rois, N, ws);
        dim3 grid(R_C, 4, NSTRIP);          // c, b, strip
        roi_strip<<<grid, 512, 0, stream>>>(input, ws, N, out);
    } else {
        int total = out_size;
        roi_align_fwd<<<(total + 255) / 256, 256, 0, stream>>>(input, rois, out, total);
    }
}